// Round 8
// baseline (1478.607 us; speedup 1.0000x reference)
//
#include <hip/hip_runtime.h>
#include <math.h>

#define H_SIZE   4096
#define N_HEADS  32
#define N_KV     8
#define HEAD_DIM 128
#define GROUP    4
#define Q_SIZE   4096
#define KV_SIZE  1024
#define QKV_OUT  6144          // Q_SIZE + 2*KV_SIZE
#define NUM_SEQS 64
#define MAX_CTX  2048
#define BLK_SZ   16
#define BLOCKS_PER_SEQ 128
#define ATT_SCALE 0.08838834764831845f   // 128^-0.5

#define CHUNK    128           // tokens per attn workgroup (4 waves x 32)
#define NCHUNK   16            // MAX_CTX / CHUNK
#define KSPLIT   8
#define KCHUNK   512           // H_SIZE / KSPLIT

typedef __attribute__((ext_vector_type(8))) short bf16x8;
typedef __attribute__((ext_vector_type(4))) float f32x4;

__device__ __forceinline__ short f2bf(float f) {
    return __builtin_bit_cast(short, (__bf16)f);   // lowers to v_cvt_pk_bf16_f32
}

__device__ __forceinline__ bf16x8 cvt8(float4 a, float4 b) {
    bf16x8 r;
    r[0]=f2bf(a.x); r[1]=f2bf(a.y); r[2]=f2bf(a.z); r[3]=f2bf(a.w);
    r[4]=f2bf(b.x); r[5]=f2bf(b.y); r[6]=f2bf(b.z); r[7]=f2bf(b.w);
    return r;
}

// ---------------- fp32 -> bf16 bulk convert (X operand, done once) ----------------
__global__ __launch_bounds__(256)
void cvt_bf16(const float* __restrict__ in, unsigned short* __restrict__ out, int n4) {
    int i = blockIdx.x * 256 + threadIdx.x;
    if (i >= n4) return;
    float4 v = *(const float4*)(in + (size_t)i * 4);
    ushort2 lo = { (unsigned short)f2bf(v.x), (unsigned short)f2bf(v.y) };
    ushort2 hi = { (unsigned short)f2bf(v.z), (unsigned short)f2bf(v.w) };
    *(ushort2*)(out + (size_t)i * 4)     = lo;
    *(ushort2*)(out + (size_t)i * 4 + 2) = hi;
}

// ---------------- MFMA GEMM: Yp[c][64][N] = A[64][4096] @ W[N][4096]^T ----------
__global__ __launch_bounds__(256)
void gemm_mfma(const unsigned short* __restrict__ A, const float* __restrict__ W,
               float* __restrict__ Yp, int N) {
    const int n0   = blockIdx.x * 64;
    const int k0   = blockIdx.y * KCHUNK;
    const int wave = threadIdx.x >> 6;
    const int lane = threadIdx.x & 63;
    const int ncol = n0 + wave * 16 + (lane & 15);
    const int klane = (lane >> 4) * 8;

    const float*          wrow = W + (size_t)ncol * H_SIZE + k0 + klane;
    const unsigned short* arow = A + (size_t)(lane & 15) * H_SIZE + k0 + klane;

    f32x4 acc[4] = {};
    for (int k = 0; k < KCHUNK; k += 32) {
        float4 wa = *(const float4*)(wrow + k);
        float4 wb = *(const float4*)(wrow + k + 4);
        bf16x8 bf = cvt8(wa, wb);
        #pragma unroll
        for (int m = 0; m < 4; ++m) {
            bf16x8 af = *(const bf16x8*)(const void*)(arow + (size_t)m * 16 * H_SIZE + k);
            acc[m] = __builtin_amdgcn_mfma_f32_16x16x32_bf16(af, bf, acc[m], 0, 0, 0);
        }
    }
    float* yp = Yp + (size_t)blockIdx.y * 64 * N;
    #pragma unroll
    for (int m = 0; m < 4; ++m)
        #pragma unroll
        for (int j = 0; j < 4; ++j)
            yp[(size_t)(m * 16 + (lane >> 4) * 4 + j) * N + ncol] = acc[m][j];
}

// ---------------- fused K-split reduce + RoPE for QKV ----------------
__global__ __launch_bounds__(256)
void qkv_reduce_rope(const float* __restrict__ Yp, float* __restrict__ qkv,
                     const int* __restrict__ positions) {
    const int s   = blockIdx.x;
    const int idx = blockIdx.y * 256 + threadIdx.x;
    const float pos = (float)positions[s];
    if (idx < 2560) {
        const int head = idx >> 6, d = idx & 63;
        const int j1 = (head < N_HEADS ? head * HEAD_DIM
                                       : Q_SIZE + (head - N_HEADS) * HEAD_DIM) + d;
        const int j2 = j1 + 64;
        float x1 = 0.f, x2 = 0.f;
        #pragma unroll
        for (int c = 0; c < KSPLIT; ++c) {
            x1 += Yp[((size_t)c * 64 + s) * QKV_OUT + j1];
            x2 += Yp[((size_t)c * 64 + s) * QKV_OUT + j2];
        }
        const float inv_freq = powf(10000.0f, -(float)d / 64.0f);
        const float ang = pos * inv_freq;
        const float cs = cosf(ang), sn = sinf(ang);
        qkv[(size_t)s * QKV_OUT + j1] = x1 * cs - x2 * sn;
        qkv[(size_t)s * QKV_OUT + j2] = x2 * cs + x1 * sn;
    } else if (idx < 3584) {
        const int j = Q_SIZE + KV_SIZE + (idx - 2560);
        float v = 0.f;
        #pragma unroll
        for (int c = 0; c < KSPLIT; ++c)
            v += Yp[((size_t)c * 64 + s) * QKV_OUT + j];
        qkv[(size_t)s * QKV_OUT + j] = v;
    }
}

__global__ __launch_bounds__(256)
void reduce_ksplit(const float* __restrict__ Yp, float* __restrict__ Y, int total) {
    int i = blockIdx.x * 256 + threadIdx.x;
    if (i >= total) return;
    float s = 0.f;
    #pragma unroll
    for (int c = 0; c < KSPLIT; ++c) s += Yp[(size_t)c * total + i];
    Y[i] = s;
}

// ---------------- Flash-decode attention, fused final reduce ----------------
// grid (NUM_SEQS*N_KV, NCHUNK); block 256 = 4 waves; chunk = 128 tokens.
// Last chunk-block per (s,h) (atomic counter) performs the cross-chunk combine.
__global__ __launch_bounds__(256)
void attn_fused(const float* __restrict__ qkv,
                const float* __restrict__ k_cache,
                const float* __restrict__ v_cache,
                const int*   __restrict__ block_tables,
                const int*   __restrict__ context_lens,
                float* __restrict__ pacc,   // [sh][c][g][128]
                float* __restrict__ pml,    // [sh][c][g][2]
                int*   __restrict__ cnt,    // [sh], pre-zeroed
                unsigned short* __restrict__ outbf) {
    const int sh = blockIdx.x;
    const int s  = sh >> 3;
    const int h  = sh & 7;
    const int c  = blockIdx.y;
    const int ctx = context_lens[s];
    const int pos = ctx - 1;
    const bool active = (c * CHUNK < ctx);

    __shared__ float qs[GROUP][HEAD_DIM];     // 2 KB
    __shared__ float sc[GROUP][CHUNK];        // 2 KB
    __shared__ float red[4][GROUP][HEAD_DIM]; // 8 KB
    __shared__ int   is_last;

    const int tid  = threadIdx.x;
    const int w    = tid >> 6;
    const int lane = tid & 63;

    if (active) {
        const int nv = min(CHUNK, ctx - c * CHUNK);

        {   // q for this group's 4 heads: 512 contiguous floats, 256 thr x float2
            int i = tid * 2;
            const float* qsrc = qkv + (size_t)s * QKV_OUT + h * (GROUP * HEAD_DIM);
            *(float2*)(&qs[i >> 7][i & 127]) = *(const float2*)(qsrc + i);
        }
        __syncthreads();

        const int*   bt   = block_tables + s * BLOCKS_PER_SEQ;
        const float* ksec = qkv + (size_t)s * QKV_OUT + Q_SIZE + h * HEAD_DIM;
        const float* vsec = qkv + (size_t)s * QKV_OUT + Q_SIZE + KV_SIZE + h * HEAD_DIM;

        // ---- K phase: token tk = w*32 + lane/2; lane&1 picks 64-dim half-row ----
        {
            const int tk   = w * 32 + (lane >> 1);
            const int half = lane & 1;
            const int T    = c * CHUNK + tk;
            float d0 = 0.f, d1 = 0.f, d2 = 0.f, d3 = 0.f;
            if (tk < nv) {
                const int blk = bt[c * (CHUNK / BLK_SZ) + (tk >> 4)];
                const float* kp = (T == pos) ? ksec
                    : k_cache + ((size_t)(blk * BLK_SZ + (tk & 15)) * N_KV + h) * HEAD_DIM;
                kp += half * 64;
                const float* q0 = &qs[0][half * 64];
                const float* q1 = &qs[1][half * 64];
                const float* q2 = &qs[2][half * 64];
                const float* q3 = &qs[3][half * 64];
                #pragma unroll
                for (int b = 0; b < 2; ++b) {
                    float4 kv[8];
                    #pragma unroll
                    for (int j = 0; j < 8; ++j) kv[j] = *(const float4*)(kp + b * 32 + j * 4);
                    #pragma unroll
                    for (int j = 0; j < 8; ++j) {
                        const float4 A = kv[j];
                        const float4 x0 = *(const float4*)(q0 + b * 32 + j * 4);
                        const float4 x1 = *(const float4*)(q1 + b * 32 + j * 4);
                        const float4 x2 = *(const float4*)(q2 + b * 32 + j * 4);
                        const float4 x3 = *(const float4*)(q3 + b * 32 + j * 4);
                        d0 = fmaf(A.x,x0.x, fmaf(A.y,x0.y, fmaf(A.z,x0.z, fmaf(A.w,x0.w, d0))));
                        d1 = fmaf(A.x,x1.x, fmaf(A.y,x1.y, fmaf(A.z,x1.z, fmaf(A.w,x1.w, d1))));
                        d2 = fmaf(A.x,x2.x, fmaf(A.y,x2.y, fmaf(A.z,x2.z, fmaf(A.w,x2.w, d2))));
                        d3 = fmaf(A.x,x3.x, fmaf(A.y,x3.y, fmaf(A.z,x3.z, fmaf(A.w,x3.w, d3))));
                    }
                }
            }
            d0 += __shfl_xor(d0, 1);
            d1 += __shfl_xor(d1, 1);
            d2 += __shfl_xor(d2, 1);
            d3 += __shfl_xor(d3, 1);
            if (half == 0) {
                const bool v = (tk < nv);
                sc[0][tk] = v ? d0 * ATT_SCALE : -1e30f;
                sc[1][tk] = v ? d1 * ATT_SCALE : -1e30f;
                sc[2][tk] = v ? d2 * ATT_SCALE : -1e30f;
                sc[3][tk] = v ? d3 * ATT_SCALE : -1e30f;
            }
        }
        __syncthreads();

        // ---- softmax: wave g owns head g (128 tokens = 2/lane) ----
        {
            const int g = w;
            const float v0 = sc[g][lane];
            const float v1 = sc[g][lane + 64];
            float m = fmaxf(v0, v1);
            #pragma unroll
            for (int off = 32; off; off >>= 1) m = fmaxf(m, __shfl_xor(m, off));
            const float e0 = __expf(v0 - m);
            const float e1 = __expf(v1 - m);
            float l = e0 + e1;
            #pragma unroll
            for (int off = 32; off; off >>= 1) l += __shfl_xor(l, off);
            sc[g][lane]      = e0;
            sc[g][lane + 64] = e1;
            if (lane == 0) {
                size_t ib = (((size_t)sh * NCHUNK + c) * GROUP + g) * 2;
                pml[ib] = m; pml[ib + 1] = l;
            }
        }
        __syncthreads();

        // ---- PV: wave w owns tokens w*32..+31; lane = dim pair ----
        {
            float2 a0 = {0,0}, a1 = {0,0}, a2 = {0,0}, a3 = {0,0};
            const int t0 = w * 32;
            const int tmax = min(32, nv - t0);
            #pragma unroll 4
            for (int tt = 0; tt < tmax; ++tt) {
                const int tk = t0 + tt;
                const int T  = c * CHUNK + tk;
                const int blk = bt[c * (CHUNK / BLK_SZ) + (tk >> 4)];
                const float* vp = (T == pos) ? vsec
                    : v_cache + ((size_t)(blk * BLK_SZ + (tk & 15)) * N_KV + h) * HEAD_DIM;
                const float2 vv = *(const float2*)(vp + lane * 2);
                const float p0 = sc[0][tk], p1 = sc[1][tk], p2 = sc[2][tk], p3 = sc[3][tk];
                a0.x = fmaf(p0, vv.x, a0.x); a0.y = fmaf(p0, vv.y, a0.y);
                a1.x = fmaf(p1, vv.x, a1.x); a1.y = fmaf(p1, vv.y, a1.y);
                a2.x = fmaf(p2, vv.x, a2.x); a2.y = fmaf(p2, vv.y, a2.y);
                a3.x = fmaf(p3, vv.x, a3.x); a3.y = fmaf(p3, vv.y, a3.y);
            }
            *(float2*)(&red[w][0][lane * 2]) = a0;
            *(float2*)(&red[w][1][lane * 2]) = a1;
            *(float2*)(&red[w][2][lane * 2]) = a2;
            *(float2*)(&red[w][3][lane * 2]) = a3;
        }
        __syncthreads();

        {   // combine 4 waves' partials: 256 thr x float2 = 4 heads x 128 dims
            const int g = tid >> 6, d = (tid & 63) * 2;
            float2 o = {0.f, 0.f};
            #pragma unroll
            for (int ww = 0; ww < 4; ++ww) {
                o.x += red[ww][g][d];
                o.y += red[ww][g][d + 1];
            }
            size_t ob = (((size_t)sh * NCHUNK + c) * GROUP + g) * HEAD_DIM + d;
            *(float2*)(pacc + ob) = o;
        }
    }

    // ---- last-block-for-(s,h) does the cross-chunk combine ----
    __threadfence();
    if (tid == 0) {
        int old = atomicAdd(&cnt[sh], 1);
        is_last = (old == NCHUNK - 1) ? 1 : 0;
    }
    __syncthreads();
    if (!is_last) return;
    __threadfence();

    {
        const int g    = tid >> 6;
        const int lane = tid & 63;
        const int nc   = (ctx + CHUNK - 1) / CHUNK;
        float M = -1e30f;
        for (int cc = 0; cc < nc; ++cc)
            M = fmaxf(M, pml[(((size_t)sh * NCHUNK + cc) * GROUP + g) * 2]);
        float ox = 0.f, oy = 0.f, L = 0.f;
        for (int cc = 0; cc < nc; ++cc) {
            size_t idx = ((size_t)sh * NCHUNK + cc) * GROUP + g;
            float wg = __expf(pml[idx * 2] - M);
            L = fmaf(wg, pml[idx * 2 + 1], L);
            float2 pa = *(const float2*)(pacc + idx * HEAD_DIM + lane * 2);
            ox = fmaf(wg, pa.x, ox);
            oy = fmaf(wg, pa.y, oy);
        }
        float inv = 1.0f / L;
        unsigned short* op = outbf + (size_t)s * Q_SIZE + (h * GROUP + g) * HEAD_DIM;
        ushort2 o2 = { (unsigned short)f2bf(ox * inv), (unsigned short)f2bf(oy * inv) };
        *(ushort2*)(op + lane * 2) = o2;
    }
}

extern "C" void kernel_launch(void* const* d_in, const int* in_sizes, int n_in,
                              void* d_out, int out_size, void* d_ws, size_t ws_size,
                              hipStream_t stream) {
    const int*   positions    = (const int*)  d_in[0];
    const float* hidden       = (const float*)d_in[1];
    const float* k_cache      = (const float*)d_in[2];
    const float* v_cache      = (const float*)d_in[3];
    const int*   block_tables = (const int*)  d_in[4];
    const int*   context_lens = (const int*)  d_in[5];
    const float* W_qkv        = (const float*)d_in[6];
    const float* W_o          = (const float*)d_in[7];
    float* out = (float*)d_out;

    float* qkv_ws = (float*)d_ws;                                     // 393216 f
    unsigned short* hidden_bf = (unsigned short*)(qkv_ws + (size_t)NUM_SEQS * QKV_OUT);
    unsigned short* attn_bf   = hidden_bf + (size_t)NUM_SEQS * H_SIZE;
    float* scratch = (float*)(attn_bf + (size_t)NUM_SEQS * H_SIZE);    // reused region
    // scratch reuse: QKV partials (3.1M f) -> attn pacc/pml (4.3M f) -> O partials (2.1M f)
    float* pacc = scratch;                                             // 512*16*4*128 f
    float* pml  = scratch + (size_t)NUM_SEQS * N_KV * NCHUNK * GROUP * HEAD_DIM;
    int*   cnt  = (int*)(scratch + 5000000);                           // dedicated slot

    // counters must be zero each call (ws not re-poisoned between replays)
    hipMemsetAsync(cnt, 0, NUM_SEQS * N_KV * sizeof(int), stream);
    // 0) X -> bf16 (once)
    cvt_bf16<<<(NUM_SEQS * H_SIZE / 4 + 255) / 256, 256, 0, stream>>>(
        hidden, hidden_bf, NUM_SEQS * H_SIZE / 4);
    // 1) QKV projection + fused reduce+RoPE
    gemm_mfma<<<dim3(QKV_OUT / 64, KSPLIT), 256, 0, stream>>>(hidden_bf, W_qkv, scratch, QKV_OUT);
    qkv_reduce_rope<<<dim3(NUM_SEQS, 14), 256, 0, stream>>>(scratch, qkv_ws, positions);
    // 2) flash-decode attention with fused final combine
    attn_fused<<<dim3(NUM_SEQS * N_KV, NCHUNK), 256, 0, stream>>>(
        qkv_ws, k_cache, v_cache, block_tables, context_lens, pacc, pml, cnt, attn_bf);
    // 3) output projection + reduce
    gemm_mfma<<<dim3(Q_SIZE / 64, KSPLIT), 256, 0, stream>>>(attn_bf, W_o, scratch, Q_SIZE);
    reduce_ksplit<<<(NUM_SEQS * Q_SIZE + 255) / 256, 256, 0, stream>>>(scratch, out, NUM_SEQS * Q_SIZE);
}

// Round 9
// 226.796 us; speedup vs baseline: 6.5195x; 6.5195x over previous
//
#include <hip/hip_runtime.h>
#include <math.h>

#define H_SIZE   4096
#define N_HEADS  32
#define N_KV     8
#define HEAD_DIM 128
#define GROUP    4
#define Q_SIZE   4096
#define KV_SIZE  1024
#define QKV_OUT  6144          // Q_SIZE + 2*KV_SIZE
#define NUM_SEQS 64
#define MAX_CTX  2048
#define BLK_SZ   16
#define BLOCKS_PER_SEQ 128
#define ATT_SCALE 0.08838834764831845f   // 128^-0.5

#define CHUNK    128           // tokens per attn workgroup (4 waves x 32)
#define NCHUNK   16            // MAX_CTX / CHUNK
#define KSPLIT   8
#define KCHUNK   512           // H_SIZE / KSPLIT

typedef __attribute__((ext_vector_type(8))) short bf16x8;
typedef __attribute__((ext_vector_type(4))) float f32x4;

__device__ __forceinline__ short f2bf(float f) {
    return __builtin_bit_cast(short, (__bf16)f);   // lowers to v_cvt_pk_bf16_f32
}

__device__ __forceinline__ bf16x8 cvt8(float4 a, float4 b) {
    bf16x8 r;
    r[0]=f2bf(a.x); r[1]=f2bf(a.y); r[2]=f2bf(a.z); r[3]=f2bf(a.w);
    r[4]=f2bf(b.x); r[5]=f2bf(b.y); r[6]=f2bf(b.z); r[7]=f2bf(b.w);
    return r;
}

// ---------------- fp32 -> bf16 bulk convert (X operand, done once) ----------------
__global__ __launch_bounds__(256)
void cvt_bf16(const float* __restrict__ in, unsigned short* __restrict__ out, int n4) {
    int i = blockIdx.x * 256 + threadIdx.x;
    if (i >= n4) return;
    float4 v = *(const float4*)(in + (size_t)i * 4);
    ushort2 lo = { (unsigned short)f2bf(v.x), (unsigned short)f2bf(v.y) };
    ushort2 hi = { (unsigned short)f2bf(v.z), (unsigned short)f2bf(v.w) };
    *(ushort2*)(out + (size_t)i * 4)     = lo;
    *(ushort2*)(out + (size_t)i * 4 + 2) = hi;
}

// ---------------- MFMA GEMM: Yp[c][64][N] = A[64][4096] @ W[N][4096]^T ----------
__global__ __launch_bounds__(256)
void gemm_mfma(const unsigned short* __restrict__ A, const float* __restrict__ W,
               float* __restrict__ Yp, int N) {
    const int n0   = blockIdx.x * 64;
    const int k0   = blockIdx.y * KCHUNK;
    const int wave = threadIdx.x >> 6;
    const int lane = threadIdx.x & 63;
    const int ncol = n0 + wave * 16 + (lane & 15);
    const int klane = (lane >> 4) * 8;

    const float*          wrow = W + (size_t)ncol * H_SIZE + k0 + klane;
    const unsigned short* arow = A + (size_t)(lane & 15) * H_SIZE + k0 + klane;

    f32x4 acc[4] = {};
    for (int k = 0; k < KCHUNK; k += 32) {
        float4 wa = *(const float4*)(wrow + k);
        float4 wb = *(const float4*)(wrow + k + 4);
        bf16x8 bf = cvt8(wa, wb);
        #pragma unroll
        for (int m = 0; m < 4; ++m) {
            bf16x8 af = *(const bf16x8*)(const void*)(arow + (size_t)m * 16 * H_SIZE + k);
            acc[m] = __builtin_amdgcn_mfma_f32_16x16x32_bf16(af, bf, acc[m], 0, 0, 0);
        }
    }
    float* yp = Yp + (size_t)blockIdx.y * 64 * N;
    #pragma unroll
    for (int m = 0; m < 4; ++m)
        #pragma unroll
        for (int j = 0; j < 4; ++j)
            yp[(size_t)(m * 16 + (lane >> 4) * 4 + j) * N + ncol] = acc[m][j];
}

// ---------------- fused K-split reduce + RoPE for QKV ----------------
__global__ __launch_bounds__(256)
void qkv_reduce_rope(const float* __restrict__ Yp, float* __restrict__ qkv,
                     const int* __restrict__ positions) {
    const int s   = blockIdx.x;
    const int idx = blockIdx.y * 256 + threadIdx.x;
    const float pos = (float)positions[s];
    if (idx < 2560) {
        const int head = idx >> 6, d = idx & 63;
        const int j1 = (head < N_HEADS ? head * HEAD_DIM
                                       : Q_SIZE + (head - N_HEADS) * HEAD_DIM) + d;
        const int j2 = j1 + 64;
        float x1 = 0.f, x2 = 0.f;
        #pragma unroll
        for (int c = 0; c < KSPLIT; ++c) {
            x1 += Yp[((size_t)c * 64 + s) * QKV_OUT + j1];
            x2 += Yp[((size_t)c * 64 + s) * QKV_OUT + j2];
        }
        const float inv_freq = powf(10000.0f, -(float)d / 64.0f);
        const float ang = pos * inv_freq;
        const float cs = cosf(ang), sn = sinf(ang);
        qkv[(size_t)s * QKV_OUT + j1] = x1 * cs - x2 * sn;
        qkv[(size_t)s * QKV_OUT + j2] = x2 * cs + x1 * sn;
    } else if (idx < 3584) {
        const int j = Q_SIZE + KV_SIZE + (idx - 2560);
        float v = 0.f;
        #pragma unroll
        for (int c = 0; c < KSPLIT; ++c)
            v += Yp[((size_t)c * 64 + s) * QKV_OUT + j];
        qkv[(size_t)s * QKV_OUT + j] = v;
    }
}

__global__ __launch_bounds__(256)
void reduce_ksplit(const float* __restrict__ Yp, float* __restrict__ Y, int total) {
    int i = blockIdx.x * 256 + threadIdx.x;
    if (i >= total) return;
    float s = 0.f;
    #pragma unroll
    for (int c = 0; c < KSPLIT; ++c) s += Yp[(size_t)c * total + i];
    Y[i] = s;
}

// ---------------- Flash-decode attention: per-chunk partials ----------------
// grid (NUM_SEQS*N_KV, NCHUNK); block 256 = 4 waves; chunk = 128 tokens.
// K phase: 2 lanes/token (contiguous 256B half-rows). PV: branch-free, 8-deep batches.
__global__ __launch_bounds__(256)
void attn_chunk(const float* __restrict__ qkv,
                const float* __restrict__ k_cache,
                const float* __restrict__ v_cache,
                const int*   __restrict__ block_tables,
                const int*   __restrict__ context_lens,
                float* __restrict__ pacc,   // [sh][c][g][128]
                float* __restrict__ pml) {  // [sh][c][g][2]
    const int sh = blockIdx.x;
    const int s  = sh >> 3;
    const int h  = sh & 7;
    const int c  = blockIdx.y;
    const int ctx = context_lens[s];
    if (c * CHUNK >= ctx) return;
    const int pos = ctx - 1;
    const int nv = min(CHUNK, ctx - c * CHUNK);

    __shared__ float qs[GROUP][HEAD_DIM];     // 2 KB
    __shared__ float sc[GROUP][CHUNK];        // 2 KB
    __shared__ float red[4][GROUP][HEAD_DIM]; // 8 KB

    const int tid  = threadIdx.x;
    const int w    = tid >> 6;
    const int lane = tid & 63;

    {   // q for this group's 4 heads: 512 contiguous floats, 256 thr x float2
        int i = tid * 2;
        const float* qsrc = qkv + (size_t)s * QKV_OUT + h * (GROUP * HEAD_DIM);
        *(float2*)(&qs[i >> 7][i & 127]) = *(const float2*)(qsrc + i);
    }
    __syncthreads();

    const int*   bt   = block_tables + s * BLOCKS_PER_SEQ;
    const float* ksec = qkv + (size_t)s * QKV_OUT + Q_SIZE + h * HEAD_DIM;
    const float* vsec = qkv + (size_t)s * QKV_OUT + Q_SIZE + KV_SIZE + h * HEAD_DIM;

    // this wave's two cache blocks (tokens w*32..w*32+15 and +16..+31)
    const int blk0 = bt[c * (CHUNK / BLK_SZ) + w * 2];
    const int blk1 = bt[c * (CHUNK / BLK_SZ) + w * 2 + 1];

    // ---- K phase: token tk = w*32 + lane/2; lane&1 picks 64-dim half-row ----
    {
        const int tk   = w * 32 + (lane >> 1);
        const int half = lane & 1;
        const int T    = c * CHUNK + tk;
        const int blk  = (lane < 32) ? blk0 : blk1;
        // loads are safe even for tk >= nv (valid table entry, garbage data)
        const float* kp = (T == pos) ? ksec
            : k_cache + ((size_t)(blk * BLK_SZ + (tk & 15)) * N_KV + h) * HEAD_DIM;
        kp += half * 64;
        const float* q0 = &qs[0][half * 64];
        const float* q1 = &qs[1][half * 64];
        const float* q2 = &qs[2][half * 64];
        const float* q3 = &qs[3][half * 64];
        float d0 = 0.f, d1 = 0.f, d2 = 0.f, d3 = 0.f;
        #pragma unroll
        for (int b = 0; b < 2; ++b) {
            float4 kv[8];
            #pragma unroll
            for (int j = 0; j < 8; ++j) kv[j] = *(const float4*)(kp + b * 32 + j * 4);
            #pragma unroll
            for (int j = 0; j < 8; ++j) {
                const float4 A = kv[j];
                const float4 x0 = *(const float4*)(q0 + b * 32 + j * 4);
                const float4 x1 = *(const float4*)(q1 + b * 32 + j * 4);
                const float4 x2 = *(const float4*)(q2 + b * 32 + j * 4);
                const float4 x3 = *(const float4*)(q3 + b * 32 + j * 4);
                d0 = fmaf(A.x,x0.x, fmaf(A.y,x0.y, fmaf(A.z,x0.z, fmaf(A.w,x0.w, d0))));
                d1 = fmaf(A.x,x1.x, fmaf(A.y,x1.y, fmaf(A.z,x1.z, fmaf(A.w,x1.w, d1))));
                d2 = fmaf(A.x,x2.x, fmaf(A.y,x2.y, fmaf(A.z,x2.z, fmaf(A.w,x2.w, d2))));
                d3 = fmaf(A.x,x3.x, fmaf(A.y,x3.y, fmaf(A.z,x3.z, fmaf(A.w,x3.w, d3))));
            }
        }
        d0 += __shfl_xor(d0, 1);
        d1 += __shfl_xor(d1, 1);
        d2 += __shfl_xor(d2, 1);
        d3 += __shfl_xor(d3, 1);
        if (half == 0) {
            const bool v = (tk < nv);
            sc[0][tk] = v ? d0 * ATT_SCALE : -1e30f;
            sc[1][tk] = v ? d1 * ATT_SCALE : -1e30f;
            sc[2][tk] = v ? d2 * ATT_SCALE : -1e30f;
            sc[3][tk] = v ? d3 * ATT_SCALE : -1e30f;
        }
    }
    __syncthreads();

    // ---- softmax: wave g owns head g (128 tokens = 2/lane) ----
    {
        const int g = w;
        const float v0 = sc[g][lane];
        const float v1 = sc[g][lane + 64];
        float m = fmaxf(v0, v1);
        #pragma unroll
        for (int off = 32; off; off >>= 1) m = fmaxf(m, __shfl_xor(m, off));
        const float e0 = __expf(v0 - m);
        const float e1 = __expf(v1 - m);
        float l = e0 + e1;
        #pragma unroll
        for (int off = 32; off; off >>= 1) l += __shfl_xor(l, off);
        sc[g][lane]      = e0;
        sc[g][lane + 64] = e1;
        if (lane == 0) {
            size_t ib = (((size_t)sh * NCHUNK + c) * GROUP + g) * 2;
            pml[ib] = m; pml[ib + 1] = l;
        }
    }
    __syncthreads();

    // ---- PV: wave w owns tokens w*32..+31; lane = dim pair; branch-free 8-deep ----
    {
        const int t0 = w * 32;
        const float* vb0 = v_cache + (size_t)blk0 * (BLK_SZ * N_KV * HEAD_DIM)
                         + (size_t)h * HEAD_DIM + lane * 2;
        const float* vb1 = v_cache + (size_t)blk1 * (BLK_SZ * N_KV * HEAD_DIM)
                         + (size_t)h * HEAD_DIM + lane * 2;
        const float* vnewp = vsec + lane * 2;
        float2 a0 = {0,0}, a1 = {0,0}, a2 = {0,0}, a3 = {0,0};
        #pragma unroll
        for (int tb = 0; tb < 32; tb += 8) {
            float2 vv[8];
            #pragma unroll
            for (int u = 0; u < 8; ++u) {
                const int tt = tb + u;                     // 0..31 compile-time
                const float* vp = (c * CHUNK + t0 + tt == pos) ? vnewp
                    : ((tt < 16 ? vb0 : vb1) + (size_t)(tt & 15) * (N_KV * HEAD_DIM));
                vv[u] = *(const float2*)vp;
            }
            #pragma unroll
            for (int u = 0; u < 8; ++u) {
                const int tk = t0 + tb + u;
                const float p0 = sc[0][tk], p1 = sc[1][tk], p2 = sc[2][tk], p3 = sc[3][tk];
                a0.x = fmaf(p0, vv[u].x, a0.x); a0.y = fmaf(p0, vv[u].y, a0.y);
                a1.x = fmaf(p1, vv[u].x, a1.x); a1.y = fmaf(p1, vv[u].y, a1.y);
                a2.x = fmaf(p2, vv[u].x, a2.x); a2.y = fmaf(p2, vv[u].y, a2.y);
                a3.x = fmaf(p3, vv[u].x, a3.x); a3.y = fmaf(p3, vv[u].y, a3.y);
            }
        }
        *(float2*)(&red[w][0][lane * 2]) = a0;
        *(float2*)(&red[w][1][lane * 2]) = a1;
        *(float2*)(&red[w][2][lane * 2]) = a2;
        *(float2*)(&red[w][3][lane * 2]) = a3;
    }
    __syncthreads();

    {   // combine 4 waves' partials: 256 thr x float2 = 4 heads x 128 dims
        const int g = tid >> 6, d = (tid & 63) * 2;
        float2 o = {0.f, 0.f};
        #pragma unroll
        for (int ww = 0; ww < 4; ++ww) {
            o.x += red[ww][g][d];
            o.y += red[ww][g][d + 1];
        }
        size_t ob = (((size_t)sh * NCHUNK + c) * GROUP + g) * HEAD_DIM + d;
        *(float2*)(pacc + ob) = o;
    }
}

// ---------------- combine chunk partials; emit bf16 for the O-GEMM ----------------
__global__ __launch_bounds__(256)
void attn_reduce(const float* __restrict__ pacc, const float* __restrict__ pml,
                 const int* __restrict__ context_lens, unsigned short* __restrict__ outbf) {
    const int sh = blockIdx.x;
    const int s  = sh >> 3;
    const int h  = sh & 7;
    const int g    = threadIdx.x >> 6;
    const int lane = threadIdx.x & 63;
    const int ctx = context_lens[s];
    const int nc  = (ctx + CHUNK - 1) / CHUNK;

    float M = -1e30f;
    for (int cc = 0; cc < nc; ++cc)
        M = fmaxf(M, pml[(((size_t)sh * NCHUNK + cc) * GROUP + g) * 2]);
    float ox = 0.f, oy = 0.f, L = 0.f;
    for (int cc = 0; cc < nc; ++cc) {
        size_t idx = ((size_t)sh * NCHUNK + cc) * GROUP + g;
        float w = __expf(pml[idx*2] - M);
        L = fmaf(w, pml[idx*2+1], L);
        float2 pa = *(const float2*)(pacc + idx * HEAD_DIM + lane*2);
        ox = fmaf(w, pa.x, ox);
        oy = fmaf(w, pa.y, oy);
    }
    float inv = 1.0f / L;
    unsigned short* op = outbf + (size_t)s * Q_SIZE + (h * GROUP + g) * HEAD_DIM;
    ushort2 o2 = { (unsigned short)f2bf(ox * inv), (unsigned short)f2bf(oy * inv) };
    *(ushort2*)(op + lane * 2) = o2;
}

extern "C" void kernel_launch(void* const* d_in, const int* in_sizes, int n_in,
                              void* d_out, int out_size, void* d_ws, size_t ws_size,
                              hipStream_t stream) {
    const int*   positions    = (const int*)  d_in[0];
    const float* hidden       = (const float*)d_in[1];
    const float* k_cache      = (const float*)d_in[2];
    const float* v_cache      = (const float*)d_in[3];
    const int*   block_tables = (const int*)  d_in[4];
    const int*   context_lens = (const int*)  d_in[5];
    const float* W_qkv        = (const float*)d_in[6];
    const float* W_o          = (const float*)d_in[7];
    float* out = (float*)d_out;

    float* qkv_ws = (float*)d_ws;                                     // 393216 f
    unsigned short* hidden_bf = (unsigned short*)(qkv_ws + (size_t)NUM_SEQS * QKV_OUT);
    unsigned short* attn_bf   = hidden_bf + (size_t)NUM_SEQS * H_SIZE;
    float* scratch = (float*)(attn_bf + (size_t)NUM_SEQS * H_SIZE);    // reused region
    // scratch reuse: QKV partials (3.1M f) -> attn pacc/pml (4.3M f) -> O partials (2.1M f)
    float* pacc = scratch;                                             // 512*16*4*128 f
    float* pml  = scratch + (size_t)NUM_SEQS * N_KV * NCHUNK * GROUP * HEAD_DIM;

    // 0) X -> bf16 (once)
    cvt_bf16<<<(NUM_SEQS * H_SIZE / 4 + 255) / 256, 256, 0, stream>>>(
        hidden, hidden_bf, NUM_SEQS * H_SIZE / 4);
    // 1) QKV projection + fused reduce+RoPE
    gemm_mfma<<<dim3(QKV_OUT / 64, KSPLIT), 256, 0, stream>>>(hidden_bf, W_qkv, scratch, QKV_OUT);
    qkv_reduce_rope<<<dim3(NUM_SEQS, 14), 256, 0, stream>>>(scratch, qkv_ws, positions);
    // 2) flash-decode attention + combine
    attn_chunk<<<dim3(NUM_SEQS * N_KV, NCHUNK), 256, 0, stream>>>(
        qkv_ws, k_cache, v_cache, block_tables, context_lens, pacc, pml);
    attn_reduce<<<NUM_SEQS * N_KV, 256, 0, stream>>>(pacc, pml, context_lens, attn_bf);
    // 3) output projection + reduce
    gemm_mfma<<<dim3(Q_SIZE / 64, KSPLIT), 256, 0, stream>>>(attn_bf, W_o, scratch, Q_SIZE);
    reduce_ksplit<<<(NUM_SEQS * Q_SIZE + 255) / 256, 256, 0, stream>>>(scratch, out, NUM_SEQS * Q_SIZE);
}